// Round 18
// baseline (5964.101 us; speedup 1.0000x reference)
//
#include <hip/hip_runtime.h>
#include <cmath>

// ---- problem constants ----
#define NB 16
#define CC 32
#define HH 256
#define WW 256
#define DD 250
#define ALPHA 2.0f     // 1 + 1/RHO
#define INVL 0.1f      // 1/L
#define THR 0.01f      // LAM/L

#define IMG_SZ (HH*WW)                       // 65536
#define IMG_TOT (NB*IMG_SZ)                  // 1,048,576
#define FLD_SZ (DD*DD)                       // 62,500
#define FLD_TOT ((size_t)NB*CC*FLD_SZ)       // 32,000,000

#define SRS 264                              // u-step LDS row stride
#define XRS 272                              // xcomp LDS row stride
#define LRS 260                              // xfield LDS row stride
#define GBD 5856                             // g-band floats per (n,c)
#define NBAND 6000                           // band pixels per image

__device__ __forceinline__ float rfl(float x) {
    return __int_as_float(__builtin_amdgcn_readfirstlane(__float_as_int(x)));
}
__device__ __forceinline__ float sthr(float v) {
    float a = fabsf(v) - THR; a = a > 0.f ? a : 0.f;
    return (v > 0.f) ? a : ((v < 0.f) ? -a : 0.f);
}

// conv: ACC[j] += wt[Aa][b]*win[b+j]
#define CONV_ROW(ACC, Aa) do { \
    _Pragma("unroll") \
    for (int b = 0; b < 7; ++b) { \
        const float wv = wt[Aa][b]; \
        ACC.x += wv*win[b+0]; ACC.y += wv*win[b+1]; \
        ACC.z += wv*win[b+2]; ACC.w += wv*win[b+3]; \
    } } while (0)

// gather: ACC[j] += wt[Aa][b]*win[8-b+j]
#define GATH_ROW(ACC, Aa) do { \
    _Pragma("unroll") \
    for (int b = 0; b < 7; ++b) { \
        const float wv = wt[Aa][b]; \
        ACC.x += wv*win[8-b+0]; ACC.y += wv*win[8-b+1]; \
        ACC.z += wv*win[8-b+2]; ACC.w += wv*win[8-b+3]; \
    } } while (0)

// ---------------------------------------------------------------------------
// k_fused: role-split blocks, grid (16, 4, NB), 512 threads.
//   role 0/1: u-step channel-half (v14 k_ustep, 16 channels)
//   role 2  : xcomp  -- Xinc = INVL*(KA (*) res), interior-exact 13x13 conv
//   role 3  : gband  -- g_c = conv(res,A_c) on border strips, 2 channels
// All roles read only `rin`; outputs disjoint. LDS union: 14256 floats.
// ---------------------------------------------------------------------------
__global__ __launch_bounds__(512) void k_fused(
    const float* __restrict__ rin,
    const float* su_cur, float* su_on,      // u^t, {u^{t-1}->u^{t+1}} aliased
    float* __restrict__ Up0, float* __restrict__ Up1,
    float* __restrict__ Xinc, float* __restrict__ gbuf,
    const float* __restrict__ Afil, const float* __restrict__ Bfil,
    const float* __restrict__ KAg,
    float cmom, int first)
{
    __shared__ __align__(16) float smem[14256];   // 57,024 B
    const int role = blockIdx.y;
    const int n    = blockIdx.z;
    const int tid  = threadIdx.x;

    if (role < 2) {
        // ================= u-step role =================
        float* resT = smem;                       // [22*SRS] = 5808
        float* st0  = smem + 5808;                // [16*SRS] = 4224
        float* st1  = smem + 10032;               // [16*SRS]

        const int p0  = blockIdx.x * 16;
        const int ch0 = role * 16;

        {
            float4 z = make_float4(0.f,0.f,0.f,0.f);
            float4* sp = (float4*)st0;
            for (int i = tid; i < 2*16*SRS/4; i += 512) sp[i] = z;
        }
        {
            const float* rb = rin + (size_t)n * IMG_SZ;
            for (int i = tid; i < 22*66; i += 512) {
                int r  = i / 66;
                int c4 = (i - r*66) << 2;
                int gr = p0 + r;
                float4 v = make_float4(0.f,0.f,0.f,0.f);
                if (gr < HH && c4 < WW) v = *(const float4*)(rb + gr*WW + c4);
                *(float4*)&resT[r*SRS + c4] = v;
            }
        }
        __syncthreads();

        const int rg  = tid >> 6;
        const int q4  = (tid & 63) << 2;
        const bool qok = (q4 <= 248);
        const int p_0 = p0 + 2*rg;

        float* img = (role ? Up1 : Up0) + (size_t)n * IMG_SZ;
        const bool momentum = (!first) && (cmom != 0.f);
        const bool plain    = (!first) && (cmom == 0.f);

        float4 ia0 = make_float4(0.f,0.f,0.f,0.f), ia1 = ia0, ia2 = ia0;

        const size_t fbase = (size_t)n * CC * FLD_SZ;
        const bool r0ok = qok && (p_0     < DD);
        const bool r1ok = qok && (p_0 + 1 < DD);
        const size_t off0 = fbase + (size_t)p_0*DD + q4;
        const size_t off1 = off0 + DD;

        for (int i16 = 0; i16 < 16; ++i16) {
            const int c = ch0 + i16;
            float wt[7][7];
            {
                const float* Wp = Bfil + c*49;
#pragma unroll
                for (int a = 0; a < 7; ++a)
#pragma unroll
                    for (int b = 0; b < 7; ++b)
                        wt[a][b] = rfl(Wp[a*7 + b]);
            }

            const size_t co = (size_t)c * FLD_SZ;
            float4 sc0 = make_float4(0.f,0.f,0.f,0.f), sc1 = sc0, so0 = sc0, so1 = sc0;
            if (momentum) {
                if (r0ok) { sc0 = *(const float4*)(su_cur + co + off0);
                            so0 = *(const float4*)(su_on  + co + off0); }
                if (r1ok) { sc1 = *(const float4*)(su_cur + co + off1);
                            so1 = *(const float4*)(su_on  + co + off1); }
            } else if (plain) {
                if (r0ok) sc0 = *(const float4*)(su_cur + co + off0);
                if (r1ok) sc1 = *(const float4*)(su_cur + co + off1);
            }

            float4 a0 = make_float4(0.f,0.f,0.f,0.f), a1 = a0;
#pragma unroll
            for (int rr = 0; rr < 8; ++rr) {
                const float* lp = &resT[(2*rg + rr)*SRS + q4];
                float4 A0 = *(const float4*)lp;
                float4 A1 = *(const float4*)(lp + 4);
                float4 A2 = *(const float4*)(lp + 8);
                const float win[12] = {A0.x,A0.y,A0.z,A0.w, A1.x,A1.y,A1.z,A1.w,
                                       A2.x,A2.y,A2.z,A2.w};
                if (rr <= 6) CONV_ROW(a0, rr);
                if (rr >= 1) CONV_ROW(a1, rr-1);
            }

            float4 o0 = make_float4(a0.x*INVL, a0.y*INVL, a0.z*INVL, a0.w*INVL);
            float4 o1 = make_float4(a1.x*INVL, a1.y*INVL, a1.z*INVL, a1.w*INVL);
            if (momentum) {
                o0.x += sc0.x + cmom*(sc0.x - so0.x);
                o0.y += sc0.y + cmom*(sc0.y - so0.y);
                o0.z += sc0.z + cmom*(sc0.z - so0.z);
                o0.w += sc0.w + cmom*(sc0.w - so0.w);
                o1.x += sc1.x + cmom*(sc1.x - so1.x);
                o1.y += sc1.y + cmom*(sc1.y - so1.y);
                o1.z += sc1.z + cmom*(sc1.z - so1.z);
                o1.w += sc1.w + cmom*(sc1.w - so1.w);
            } else if (plain) {
                o0.x += sc0.x; o0.y += sc0.y; o0.z += sc0.z; o0.w += sc0.w;
                o1.x += sc1.x; o1.y += sc1.y; o1.z += sc1.z; o1.w += sc1.w;
            }
            o0.x = sthr(o0.x); o0.y = sthr(o0.y); o0.z = sthr(o0.z); o0.w = sthr(o0.w);
            o1.x = sthr(o1.x); o1.y = sthr(o1.y); o1.z = sthr(o1.z); o1.w = sthr(o1.w);

            float* stb = (i16 & 1) ? st1 : st0;
            if (r0ok) {
                float* dst = su_on + co + off0;
                if (q4 <= 244) *(float4*)dst = o0;
                else           *(float2*)dst = make_float2(o0.x, o0.y);
                float* d0 = &stb[(2*rg)*SRS + q4 + 8];
                if (q4 <= 244) *(float4*)d0 = o0;
                else           *(float2*)d0 = make_float2(o0.x, o0.y);
            }
            if (r1ok) {
                float* dst = su_on + co + off1;
                if (q4 <= 244) *(float4*)dst = o1;
                else           *(float2*)dst = make_float2(o1.x, o1.y);
                float* d1 = &stb[(2*rg + 1)*SRS + q4 + 8];
                if (q4 <= 244) *(float4*)d1 = o1;
                else           *(float2*)d1 = make_float2(o1.x, o1.y);
            }
            __syncthreads();

#pragma unroll
            for (int k9 = 0; k9 < 9; ++k9) {
                const int k = 3*rg - 6 + k9;
                if (k >= 0 && k < 16) {
                    const float* sp = &stb[k*SRS + q4];
                    float4 B0 = *(const float4*)sp;
                    float4 B1 = *(const float4*)(sp + 4);
                    float4 B2 = *(const float4*)(sp + 8);
                    const float win[12] = {B0.x,B0.y,B0.z,B0.w, B1.x,B1.y,B1.z,B1.w,
                                           B2.x,B2.y,B2.z,B2.w};
                    if (k9 <= 6)            GATH_ROW(ia0, 6 - k9);
                    if (k9 >= 1 && k9 <= 7) GATH_ROW(ia1, 7 - k9);
                    if (k9 >= 2)            GATH_ROW(ia2, 8 - k9);
                }
            }
        }

#pragma unroll
        for (int d = 0; d < 3; ++d) {
            const int h = 3*rg + d;
            if (h < 22) {
                const int habs = p0 + h;
                if (habs < HH) {
                    float4 v = (d == 0) ? ia0 : (d == 1) ? ia1 : ia2;
                    float* ip = img + (size_t)habs*WW + q4;
                    if (h >= 6 && h <= 15) {
                        *(float4*)ip = v;
                    } else {
                        atomicAdd(ip + 0, v.x);
                        atomicAdd(ip + 1, v.y);
                        atomicAdd(ip + 2, v.z);
                        atomicAdd(ip + 3, v.w);
                    }
                }
            }
        }
    } else if (role == 2) {
        // ================= xcomp role (512 threads) =================
        float* rt = smem;                         // [28*XRS] = 7616
        float* ka = smem + 28*XRS;                // [169]

        const int h0 = blockIdx.x * 16;
        if (tid < 169) ka[tid] = KAg[tid];
        for (int i = tid; i < 28*16; i += 512) {  // zero pads cols 0..7,264..271
            int r = i >> 4, j = i & 15;
            rt[r*XRS + ((j < 8) ? j : (256 + j))] = 0.f;
        }
        {
            const float* rb = rin + (size_t)n * IMG_SZ;
            for (int i = tid; i < 28*64; i += 512) {
                int r = i >> 6, c4 = (i & 63) << 2;
                int gr = h0 - 6 + r;
                float4 v = make_float4(0.f,0.f,0.f,0.f);
                if (gr >= 0 && gr < HH) v = *(const float4*)(rb + gr*WW + c4);
                *(float4*)&rt[r*XRS + 8 + c4] = v;
            }
        }
        __syncthreads();

        const int tq = tid & 63;
        const int hg = tid >> 6;                  // 0..7, 2 rows each
        const int w4 = tq << 2;

        float acc[2][4];
#pragma unroll
        for (int r = 0; r < 2; ++r)
#pragma unroll
            for (int j = 0; j < 4; ++j) acc[r][j] = 0.f;

#pragma unroll
        for (int k = 0; k < 14; ++k) {
            const float* lp = &rt[(hg*2 + k)*XRS + w4];
            float4 W0 = *(const float4*)lp;
            float4 W1 = *(const float4*)(lp + 4);
            float4 W2 = *(const float4*)(lp + 8);
            float4 W3 = *(const float4*)(lp + 12);
            float4 W4 = *(const float4*)(lp + 16);
            const float win[20] = {W0.x,W0.y,W0.z,W0.w, W1.x,W1.y,W1.z,W1.w,
                                   W2.x,W2.y,W2.z,W2.w, W3.x,W3.y,W3.z,W3.w,
                                   W4.x,W4.y,W4.z,W4.w};
#pragma unroll
            for (int r = 0; r < 2; ++r) {
                const int dyk = k - r;
                if (dyk >= 0 && dyk <= 12) {
                    const float* kr = &ka[dyk*13];
#pragma unroll
                    for (int dx = 0; dx < 13; ++dx) {
                        const float kv = kr[dx];
                        acc[r][0] += kv * win[2 + dx + 0];
                        acc[r][1] += kv * win[2 + dx + 1];
                        acc[r][2] += kv * win[2 + dx + 2];
                        acc[r][3] += kv * win[2 + dx + 3];
                    }
                }
            }
        }

#pragma unroll
        for (int r = 0; r < 2; ++r) {
            const int h = h0 + hg*2 + r;
            const size_t o = (size_t)n*IMG_SZ + (size_t)h*WW + w4;
            *(float4*)(Xinc + o) = make_float4(acc[r][0]*INVL, acc[r][1]*INVL,
                                               acc[r][2]*INVL, acc[r][3]*INVL);
        }
    } else {
        // ================= gband role (2 channels) =================
        const int c0 = blockIdx.x * 2;
        const float* rb = rin + (size_t)n * IMG_SZ;
#pragma unroll
        for (int cc2 = 0; cc2 < 2; ++cc2) {
            const int c = c0 + cc2;
            float wt[7][7];
            {
                const float* Wp = Afil + c*49;
#pragma unroll
                for (int a = 0; a < 7; ++a)
#pragma unroll
                    for (int b = 0; b < 7; ++b)
                        wt[a][b] = rfl(Wp[a*7 + b]);
            }
            float* gp = gbuf + ((size_t)(n*CC + c)) * GBD;
            for (int i = tid; i < GBD; i += 512) {
                int k, l;
                if (i < 3000) {
                    int kk = i / 250;
                    k = (kk < 6) ? kk : 238 + kk;
                    l = i - kk*250;
                } else {
                    int j = i - 3000;
                    int r = j / 12, cc = j - r*12;
                    k = 6 + r;
                    l = (cc < 6) ? cc : 238 + cc;
                }
                float s = 0.f;
#pragma unroll
                for (int p = 0; p < 7; ++p)
#pragma unroll
                    for (int q = 0; q < 7; ++q)
                        s += wt[p][q] * rb[(k+p)*WW + (l+q)];
                gp[i] = s;
            }
        }
    }
}

// strip lookup for gbuf
__device__ __forceinline__ int gidx(int k, int l) {
    if (k <= 5)   return k*250 + l;
    if (k >= 244) return (k - 238)*250 + l;
    return 3000 + (k - 6)*12 + ((l <= 5) ? l : l - 238);
}

// ---------------------------------------------------------------------------
// k_xband: one thread per (band-pixel, channel); 8 px x 32 ch per block;
// channel-sum via shfl_xor; lane c==0 stores. grid ((NBAND+7)/8, NB).
// ---------------------------------------------------------------------------
__global__ __launch_bounds__(256) void k_xband(
    const float* __restrict__ gbuf, float* __restrict__ Xinc,
    const float* __restrict__ Afil)
{
    __shared__ float wA[CC*49];
    const int n   = blockIdx.y;
    const int tid = threadIdx.x;
    for (int i = tid; i < CC*49; i += 256) wA[i] = Afil[i];
    __syncthreads();

    const int px = tid >> 5;
    const int c  = tid & 31;
    const int i  = blockIdx.x*8 + px;
    if (i >= NBAND) return;

    int h, w;
    if (i < 3072) {
        int r = i >> 8;
        h = (r < 6) ? r : 244 + r;
        w = i & 255;
    } else {
        int j = i - 3072;
        int r = j / 12, cc = j - r*12;
        h = 6 + r;
        w = (cc < 6) ? cc : 244 + cc;
    }

    const float* wc = &wA[c*49];
    const float* gc = gbuf + ((size_t)n * CC + c) * GBD;
    float s = 0.f;
#pragma unroll
    for (int a = 0; a < 7; ++a) {
        int k = h - a;
        if (k < 0 || k > 249) continue;
#pragma unroll
        for (int b = 0; b < 7; ++b) {
            int l = w - b;
            if (l < 0 || l > 249) continue;
            s += wc[a*7 + b] * gc[gidx(k, l)];
        }
    }
    for (int m = 16; m >= 1; m >>= 1) s += __shfl_xor(s, m, 32);
    if (c == 0)
        Xinc[(size_t)n*IMG_SZ + (size_t)h*WW + w] = s * INVL;
}

// ---------------------------------------------------------------------------
// k_res (iteration t = 1..14):
//   X^t = (1+cb)X^{t-1} - cb*X^{t-2} + Xinc^{t-1}      (cb = cv[t-2], 0 @t<=2)
//   U^t = Up0 + Up1 (then zeroed)
//   res = y - ALPHA*((1+cm)X^t - cm*X^{t-1}) - ((1+cm)U^t - cm*U^{t-1})
//   Racc += alpha_t * res;  Uc := U^t.
// ---------------------------------------------------------------------------
__global__ __launch_bounds__(256) void k_res(
    const float* __restrict__ y,
    const float* __restrict__ Xinc,
    float* Up0, float* Up1,
    const float* __restrict__ XAv,
    float* XBv,
    float* Uc,
    float* __restrict__ resb, float* __restrict__ Racc,
    float cb, float cm, float alf)
{
    int i = blockIdx.x*256 + threadIdx.x;
    if (i >= IMG_TOT/4) return;
    float4 z = make_float4(0.f,0.f,0.f,0.f);

    float4 xi = ((const float4*)Xinc)[i];
    float4 u0 = ((const float4*)Up0)[i];  ((float4*)Up0)[i] = z;
    float4 u1 = ((const float4*)Up1)[i];  ((float4*)Up1)[i] = z;
    float4 ua = make_float4(u0.x+u1.x, u0.y+u1.y, u0.z+u1.z, u0.w+u1.w);
    float4 xa = ((const float4*)XAv)[i];

    float4 xt;
    if (cb != 0.f) {
        float4 xb = ((const float4*)XBv)[i];
        const float cbp = 1.f + cb;
        xt.x = cbp*xa.x - cb*xb.x + xi.x;
        xt.y = cbp*xa.y - cb*xb.y + xi.y;
        xt.z = cbp*xa.z - cb*xb.z + xi.z;
        xt.w = cbp*xa.w - cb*xb.w + xi.w;
    } else {
        xt.x = xa.x + xi.x; xt.y = xa.y + xi.y;
        xt.z = xa.z + xi.z; xt.w = xa.w + xi.w;
    }
    ((float4*)XBv)[i] = xt;

    float4 ucp = z;
    if (cm != 0.f) ucp = ((const float4*)Uc)[i];
    ((float4*)Uc)[i] = ua;

    float4 yv = ((const float4*)y)[i];
    const float cp = 1.f + cm;
    float4 r;
    r.x = yv.x - ALPHA*(cp*xt.x - cm*xa.x) - (cp*ua.x - cm*ucp.x);
    r.y = yv.y - ALPHA*(cp*xt.y - cm*xa.y) - (cp*ua.y - cm*ucp.y);
    r.z = yv.z - ALPHA*(cp*xt.z - cm*xa.z) - (cp*ua.z - cm*ucp.z);
    r.w = yv.w - ALPHA*(cp*xt.w - cm*xa.w) - (cp*ua.w - cm*ucp.w);
    ((float4*)resb)[i] = r;

    float4 ra = ((const float4*)Racc)[i];
    ra.x += alf*r.x; ra.y += alf*r.y; ra.z += alf*r.z; ra.w += alf*r.w;
    ((float4*)Racc)[i] = ra;
}

// ---------------------------------------------------------------------------
// k_kernA: K_A[dy+6][dx+6] = sum_c sum_{a,b valid} A[c][a][b]*A[c][a+dy][b+dx]
// ---------------------------------------------------------------------------
__global__ void k_kernA(const float* __restrict__ A, float* __restrict__ KA)
{
    int t = threadIdx.x;
    if (t >= 169) return;
    int dy = t / 13 - 6, dx = t % 13 - 6;
    float s = 0.f;
    for (int c = 0; c < CC; ++c) {
        const float* Ac = A + c*49;
        for (int a = 0; a < 7; ++a) {
            int aa = a + dy;
            if (aa < 0 || aa > 6) continue;
            for (int b = 0; b < 7; ++b) {
                int bb = b + dx;
                if (bb < 0 || bb > 6) continue;
                s += Ac[a*7 + b] * Ac[aa*7 + bb];
            }
        }
    }
    KA[t] = s;
}

// ---------------------------------------------------------------------------
// k_xfield: x_15 = INVL * conv(Racc + alf0*y, A)   (one-shot, all channels)
// ---------------------------------------------------------------------------
__global__ __launch_bounds__(256) void k_xfield(
    const float* __restrict__ Racc, const float* __restrict__ yimg,
    float* __restrict__ xout, const float* __restrict__ Afil, float alf0)
{
    __shared__ float lr[22*LRS + 8];

    const int c   = blockIdx.x;
    const int p0  = blockIdx.y * 16;
    const int n   = blockIdx.z;
    const int tid = threadIdx.x;

    const float* rb = Racc + (size_t)n * IMG_SZ;
    const float* yb = yimg + (size_t)n * IMG_SZ;
#pragma unroll
    for (int it = 0; it < 6; ++it) {
        int idx = tid + it*256;
        if (idx < 22*64) {
            int r = idx >> 6, c4 = (idx & 63) << 2;
            int gr = p0 + r;
            float4 v = make_float4(0.f,0.f,0.f,0.f);
            if (gr < HH) {
                float4 a = *(const float4*)(rb + gr*WW + c4);
                float4 b = *(const float4*)(yb + gr*WW + c4);
                v.x = a.x + alf0*b.x; v.y = a.y + alf0*b.y;
                v.z = a.z + alf0*b.z; v.w = a.w + alf0*b.w;
            }
            *(float4*)&lr[r*LRS + c4] = v;
        }
    }
    if (tid < 8) lr[22*LRS + tid] = 0.f;

    float wt[7][7];
    {
        const float* Wp = Afil + c*49;
#pragma unroll
        for (int a = 0; a < 7; ++a)
#pragma unroll
            for (int b = 0; b < 7; ++b)
                wt[a][b] = rfl(Wp[a*7 + b]);
    }
    __syncthreads();

    const int tq = tid & 63;
    const int pg = tid >> 6;
    const int q4 = tq << 2;

    float acc4[4][4];
#pragma unroll
    for (int k = 0; k < 4; ++k)
#pragma unroll
        for (int j = 0; j < 4; ++j) acc4[k][j] = 0.f;

#pragma unroll
    for (int rr = 0; rr < 10; ++rr) {
        const float* lp = &lr[(pg*4 + rr)*LRS + q4];
        float4 A0 = *(const float4*)lp;
        float4 A1 = *(const float4*)(lp + 4);
        float4 A2 = *(const float4*)(lp + 8);
        const float win[12] = {A0.x,A0.y,A0.z,A0.w, A1.x,A1.y,A1.z,A1.w,
                               A2.x,A2.y,A2.z,A2.w};
#pragma unroll
        for (int k = 0; k < 4; ++k) {
            const int a = rr - k;
            if (a >= 0 && a < 7) {
                float4 t = make_float4(acc4[k][0], acc4[k][1], acc4[k][2], acc4[k][3]);
                CONV_ROW(t, a);
                acc4[k][0] = t.x; acc4[k][1] = t.y; acc4[k][2] = t.z; acc4[k][3] = t.w;
            }
        }
    }

    const size_t base = ((size_t)n*CC + c) * FLD_SZ;
#pragma unroll
    for (int k = 0; k < 4; ++k) {
        int p = p0 + pg*4 + k;
        if (p < DD) {
            size_t off = base + (size_t)p*DD + q4;
            float4 o = make_float4(acc4[k][0]*INVL, acc4[k][1]*INVL,
                                   acc4[k][2]*INVL, acc4[k][3]*INVL);
            if (q4 <= 244)      *(float4*)(xout + off) = o;
            else if (q4 == 248) *(float2*)(xout + off) = make_float2(o.x, o.y);
        }
    }
}

__global__ __launch_bounds__(256) void k_zero4(float* a, float* b, float* c, float* d)
{
    int i = blockIdx.x*256 + threadIdx.x;
    if (i < IMG_TOT/4) {
        float4 z = make_float4(0.f,0.f,0.f,0.f);
        ((float4*)a)[i] = z;
        ((float4*)b)[i] = z;
        ((float4*)c)[i] = z;
        ((float4*)d)[i] = z;
    }
}

// k_finale: X^15 = (1+cb)X^14 - cb*X^13 + Xinc^14; U^15 = Up0+Up1;
// axh = X^15; buh = U^15; yhat = X^15 + U^15.
__global__ __launch_bounds__(256) void k_finale(
    const float* __restrict__ Xinc,
    const float* __restrict__ Up0, const float* __restrict__ Up1,
    const float* __restrict__ XA, const float* __restrict__ XB, float cb,
    float* __restrict__ axh, float* __restrict__ buh, float* __restrict__ yhat)
{
    int i = blockIdx.x*256 + threadIdx.x;
    if (i >= IMG_TOT/4) return;
    float4 xi = ((const float4*)Xinc)[i];
    float4 xa = ((const float4*)XA)[i];
    float4 xb = ((const float4*)XB)[i];
    float4 u0 = ((const float4*)Up0)[i];
    float4 u1 = ((const float4*)Up1)[i];
    float4 u  = make_float4(u0.x+u1.x, u0.y+u1.y, u0.z+u1.z, u0.w+u1.w);
    const float cbp = 1.f + cb;
    float4 xt;
    xt.x = cbp*xa.x - cb*xb.x + xi.x;
    xt.y = cbp*xa.y - cb*xb.y + xi.y;
    xt.z = cbp*xa.z - cb*xb.z + xi.z;
    xt.w = cbp*xa.w - cb*xb.w + xi.w;
    ((float4*)axh)[i] = xt;
    ((float4*)buh)[i] = u;
    float4 s = make_float4(xt.x+u.x, xt.y+u.y, xt.z+u.z, xt.w+u.w);
    ((float4*)yhat)[i] = s;
}

extern "C" void kernel_launch(void* const* d_in, const int* in_sizes, int n_in,
                              void* d_out, int out_size, void* d_ws, size_t ws_size,
                              hipStream_t stream) {
    const float* y = (const float*)d_in[0];
    const float* A = (const float*)d_in[1];
    const float* B = (const float*)d_in[2];

    float* out  = (float*)d_out;
    float* yhat = out;                          // [IMG_TOT]
    float* xout = out + IMG_TOT;                // [FLD_TOT]  x_15
    float* uout = xout + FLD_TOT;               // [FLD_TOT]  u_15
    float* axh  = uout + FLD_TOT;               // [IMG_TOT]  Ax_hat (end only)
    float* buh  = axh + IMG_TOT;                // [IMG_TOT]  Bu_hat (end only)

    float* ws   = (float*)d_ws;                 // ~170 MB
    float* Pu0  = ws;                           // [FLD_TOT]
    float* XP0  = Pu0 + FLD_TOT;                // [IMG_TOT]  X even gens (X^0=0)
    float* XP1  = XP0 + IMG_TOT;                // [IMG_TOT]  X odd gens
    float* Uc   = XP1 + IMG_TOT;                // [IMG_TOT]  U^{t-1}
    float* Up0  = Uc + IMG_TOT;                 // [IMG_TOT]  U partial (half 0)
    float* Up1  = Up0 + IMG_TOT;                // [IMG_TOT]  U partial (half 1)
    float* Racc = Up1 + IMG_TOT;                // [IMG_TOT]  sum alpha_t*res_t
    float* Xinc = Racc + IMG_TOT;               // [IMG_TOT]  convT(conv(res,A))/L
    float* gbuf = Xinc + IMG_TOT;               // [NB*CC*GBD]
    float* KA   = gbuf + (size_t)NB*CC*GBD;     // [169]

    float* Pu[2] = {Pu0, uout};                 // u^t in Pu[t&1]; u^15 -> uout
    float* XP[2] = {XP0, XP1};                  // X^t in XP[t&1]
    float* res   = yhat;                        // borrowed; rewritten by finale

    // FISTA momentum coefficients; step t uses cm=cv[t-1]; cv[0]==0.
    float cv[15];
    {
        float t = 1.0f;
        for (int k = 0; k < 15; ++k) {
            float tn = (1.0f + sqrtf(1.0f + 4.0f*t*t)) * 0.5f;
            cv[k] = (t - 1.0f) / tn;
            t = tn;
        }
    }
    // alpha: x_15 = sum_s alpha[s]*g_s, g_s = INVL*conv(res_s, A).
    float alpha[15];
    {
        double bp[15] = {0}, bc[15] = {0}, bn[15];
        bc[0] = 1.0;
        for (int t = 1; t < 15; ++t) {
            double cm = (double)cv[t-1];
            for (int s = 0; s < 15; ++s) bn[s] = (1.0+cm)*bc[s] - cm*bp[s];
            bn[t] += 1.0;
            for (int s = 0; s < 15; ++s) { bp[s] = bc[s]; bc[s] = bn[s]; }
        }
        for (int s = 0; s < 15; ++s) alpha[s] = (float)bc[s];
    }

    dim3 blk512(512), blk256(256);
    dim3 gF(16, 4, NB);                         // fused: ustep x2, xcomp, gband
    dim3 gXB((NBAND + 7)/8, NB);
    int  gE = (IMG_TOT/4 + 255)/256;

    k_zero4<<<gE, blk256, 0, stream>>>(XP0, Up0, Up1, Racc);
    k_kernA<<<1, 256, 0, stream>>>(A, KA);

    // t = 0: res == y
    k_fused<<<gF, blk512, 0, stream>>>(y, Pu[0], Pu[1], Up0, Up1,
                                       Xinc, gbuf, A, B, KA, 0.0f, 1);
    k_xband<<<gXB, blk256, 0, stream>>>(gbuf, Xinc, A);

    for (int t = 1; t < 15; ++t) {
        const float cm = cv[t-1];
        const float cb = (t >= 2) ? cv[t-2] : 0.0f;
        k_res<<<gE, blk256, 0, stream>>>(y, Xinc, Up0, Up1,
                                         XP[(t-1)&1], XP[t&1], Uc,
                                         res, Racc, cb, cm, alpha[t]);
        k_fused<<<gF, blk512, 0, stream>>>(res, Pu[t&1], Pu[(t+1)&1], Up0, Up1,
                                           Xinc, gbuf, A, B, KA, cm, 0);
        k_xband<<<gXB, blk256, 0, stream>>>(gbuf, Xinc, A);
    }

    // endgame: x_15 field from weighted residuals; X^15/U^15 images + yhat.
    k_xfield<<<dim3(CC, 16, NB), blk256, 0, stream>>>(Racc, y, xout, A, alpha[0]);
    k_finale<<<gE, blk256, 0, stream>>>(Xinc, Up0, Up1, XP[0], XP[1], cv[13],
                                        axh, buh, yhat);
}

// Round 19
// 3856.821 us; speedup vs baseline: 1.5464x; 1.5464x over previous
//
#include <hip/hip_runtime.h>
#include <cmath>

// ---- problem constants ----
#define NB 16
#define CC 32          // channels per dictionary (A and B each)
#define HH 256
#define WW 256
#define DD 250         // 256 - 7 + 1
#define ALPHA 2.0f     // 1 + 1/RHO
#define INVL 0.1f      // 1/L
#define THR 0.01f      // LAM/L

#define IMG_SZ (HH*WW)                       // 65536
#define IMG_TOT (NB*IMG_SZ)                  // 1,048,576
#define FLD_SZ (DD*DD)                       // 62,500
#define FLD_TOT ((size_t)NB*CC*FLD_SZ)       // 32,000,000

#define SRS 264                              // LDS row stride (floats)

// block-uniform float -> SGPR (filter taps become the s-operand of v_fma)
__device__ __forceinline__ float rfl(float x) {
    return __int_as_float(__builtin_amdgcn_readfirstlane(__float_as_int(x)));
}
__device__ __forceinline__ float sthr(float v) {
    float a = fabsf(v) - THR; a = a > 0.f ? a : 0.f;
    return (v > 0.f) ? a : ((v < 0.f) ? -a : 0.f);
}

// conv: out[e][j] += wt[a][b] * res[row][q4 + b + j]   (win = res cols q4..q4+11)
#define CONV_ROW(ACC, Aa) do { \
    _Pragma("unroll") \
    for (int b = 0; b < 7; ++b) { \
        const float wv = wt[Aa][b]; \
        ACC.x += wv*win[b+0]; ACC.y += wv*win[b+1]; \
        ACC.z += wv*win[b+2]; ACC.w += wv*win[b+3]; \
    } } while (0)

// gather (convT): img[d][j] += wt[a][b] * s[k][w4 + j - b]
// win = stile cols (cs) w4..w4+11 where cs = scol + 8 -> idx = 8 + j - b
#define GATH_ROW(ACC, Aa) do { \
    _Pragma("unroll") \
    for (int b = 0; b < 7; ++b) { \
        const float wv = wt[Aa][b]; \
        ACC.x += wv*win[8-b+0]; ACC.y += wv*win[8-b+1]; \
        ACC.z += wv*win[8-b+2]; ACC.w += wv*win[8-b+3]; \
    } } while (0)

// ---------------------------------------------------------------------------
// k_step: FUSED update + convT (v8, proven 4.22 ms) with __launch_bounds__
// (512, 4): VGPR cap 64 (was 72) -> +1 wave/SIMD of latency hiding.
// Block = (p-tile of 16 rows, field, n), 512 threads, all 32 channels.
// Per channel c:
//   conv(res_tile, W_c) -> s_next (2 rows x 4 cols / thread)  [weights->SGPR]
//   s_next -> global field AND double-buffered LDS s-tile
//   gather: img_acc(regs, 3 rows x 4 cols / thread) += convT(s_tile, W_c)
// End: img rows [6,15] (exclusive owner) plain-stored; boundary rows [0,5],
// [16,21] atomicAdd into the zeroed image accumulators.
// ---------------------------------------------------------------------------
__global__ __launch_bounds__(512, 4) void k_step(
    const float* __restrict__ rin,          // res image (or y at step 0)
    const float* sx_cur, const float* su_cur,
    float* sx_on, float* su_on,             // s_old == s_next (read then write)
    float* __restrict__ Ximg, float* __restrict__ Uimg,  // accumulated convT images
    const float* __restrict__ Afil, const float* __restrict__ Bfil,
    float cmom, int first)
{
    __shared__ __align__(16) float resT[22*SRS];
    __shared__ __align__(16) float stile[2][16*SRS];

    const int p0  = blockIdx.x * 16;
    const int f   = blockIdx.y;
    const int n   = blockIdx.z;
    const int tid = threadIdx.x;
    const bool isx = (f == 0);

    // zero both s-tile buffers (borders + beyond-DD rows rely on this)
    {
        float4 z = make_float4(0.f,0.f,0.f,0.f);
        float4* sp = (float4*)&stile[0][0];
        for (int i = tid; i < 2*16*SRS/4; i += 512) sp[i] = z;
    }
    // stage res tile rows [p0 .. p0+21], cols 0..255 (+8 zero cols pad)
    {
        const float* rb = rin + (size_t)n * IMG_SZ;
        for (int i = tid; i < 22*66; i += 512) {
            int r  = i / 66;
            int c4 = (i - r*66) << 2;
            int gr = p0 + r;
            float4 v = make_float4(0.f,0.f,0.f,0.f);
            if (gr < HH && c4 < WW) v = *(const float4*)(rb + gr*WW + c4);
            *(float4*)&resT[r*SRS + c4] = v;
        }
    }
    __syncthreads();

    const int rg  = tid >> 6;               // 0..7 (wave-uniform)
    const int q4  = (tid & 63) << 2;        // 0..252
    const bool qok = (q4 <= 248);           // q4==252 lanes idle for conv/state
    const int p_0 = p0 + 2*rg;              // conv output rows p_0, p_0+1

    const float* Wb   = isx ? Afil : Bfil;
    const float* scur = isx ? sx_cur : su_cur;
    float*       sON  = isx ? sx_on  : su_on;    // old AND next
    float*       img  = (isx ? Ximg : Uimg) + (size_t)n * IMG_SZ;

    const bool momentum = (!first) && (cmom != 0.f);
    const bool plain    = (!first) && (cmom == 0.f);

    float4 ia0 = make_float4(0.f,0.f,0.f,0.f), ia1 = ia0, ia2 = ia0;

    const size_t fbase = (size_t)n * CC * FLD_SZ;
    const bool r0ok = qok && (p_0     < DD);
    const bool r1ok = qok && (p_0 + 1 < DD);
    const size_t off0 = fbase + (size_t)p_0*DD + q4;       // + c*FLD_SZ
    const size_t off1 = off0 + DD;

    for (int c = 0; c < CC; ++c) {
        // filter taps -> SGPRs
        float wt[7][7];
        {
            const float* Wp = Wb + c*49;
#pragma unroll
            for (int a = 0; a < 7; ++a)
#pragma unroll
                for (int b = 0; b < 7; ++b)
                    wt[a][b] = rfl(Wp[a*7 + b]);
        }

        // state loads early (float4 reads may overhang 2 floats into the
        // adjacent buffer at q4==248 -- memory-safe by layout; .zw unused)
        const size_t co = (size_t)c * FLD_SZ;
        float4 sc0 = make_float4(0.f,0.f,0.f,0.f), sc1 = sc0, so0 = sc0, so1 = sc0;
        if (momentum) {
            if (r0ok) { sc0 = *(const float4*)(scur + co + off0);
                        so0 = *(const float4*)(sON  + co + off0); }
            if (r1ok) { sc1 = *(const float4*)(scur + co + off1);
                        so1 = *(const float4*)(sON  + co + off1); }
        } else if (plain) {
            if (r0ok) sc0 = *(const float4*)(scur + co + off0);
            if (r1ok) sc1 = *(const float4*)(scur + co + off1);
        }

        // conv: rows p_0, p_0+1 from res rows (2rg .. 2rg+7)
        float4 a0 = make_float4(0.f,0.f,0.f,0.f), a1 = a0;
#pragma unroll
        for (int rr = 0; rr < 8; ++rr) {
            const float* lp = &resT[(2*rg + rr)*SRS + q4];
            float4 A0 = *(const float4*)lp;
            float4 A1 = *(const float4*)(lp + 4);
            float4 A2 = *(const float4*)(lp + 8);
            const float win[12] = {A0.x,A0.y,A0.z,A0.w, A1.x,A1.y,A1.z,A1.w,
                                   A2.x,A2.y,A2.z,A2.w};
            if (rr <= 6) CONV_ROW(a0, rr);       // e=0: a = rr
            if (rr >= 1) CONV_ROW(a1, rr-1);     // e=1: a = rr-1
        }

        // epilogue: s_next values
        float4 o0 = make_float4(a0.x*INVL, a0.y*INVL, a0.z*INVL, a0.w*INVL);
        float4 o1 = make_float4(a1.x*INVL, a1.y*INVL, a1.z*INVL, a1.w*INVL);
        if (momentum) {
            o0.x += sc0.x + cmom*(sc0.x - so0.x);
            o0.y += sc0.y + cmom*(sc0.y - so0.y);
            o0.z += sc0.z + cmom*(sc0.z - so0.z);
            o0.w += sc0.w + cmom*(sc0.w - so0.w);
            o1.x += sc1.x + cmom*(sc1.x - so1.x);
            o1.y += sc1.y + cmom*(sc1.y - so1.y);
            o1.z += sc1.z + cmom*(sc1.z - so1.z);
            o1.w += sc1.w + cmom*(sc1.w - so1.w);
        } else if (plain) {
            o0.x += sc0.x; o0.y += sc0.y; o0.z += sc0.z; o0.w += sc0.w;
            o1.x += sc1.x; o1.y += sc1.y; o1.z += sc1.z; o1.w += sc1.w;
        }
        if (!isx) {
            o0.x = sthr(o0.x); o0.y = sthr(o0.y); o0.z = sthr(o0.z); o0.w = sthr(o0.w);
            o1.x = sthr(o1.x); o1.y = sthr(o1.y); o1.z = sthr(o1.z); o1.w = sthr(o1.w);
        }

        // global store of s_next
        if (r0ok) {
            float* dst = sON + co + off0;
            if (q4 <= 244) *(float4*)dst = o0;
            else           *(float2*)dst = make_float2(o0.x, o0.y);
        }
        if (r1ok) {
            float* dst = sON + co + off1;
            if (q4 <= 244) *(float4*)dst = o1;
            else           *(float2*)dst = make_float2(o1.x, o1.y);
        }

        // s-tile write (1 barrier/channel: gather(c-2) on this buffer is
        // separated by the barriers of iterations c-2 and c-1)
        const int bb = c & 1;
        if (r0ok) {
            float* d0 = &stile[bb][(2*rg)*SRS + q4 + 8];
            if (q4 <= 244) *(float4*)d0 = o0;
            else           *(float2*)d0 = make_float2(o0.x, o0.y);
        }
        if (r1ok) {
            float* d1 = &stile[bb][(2*rg + 1)*SRS + q4 + 8];
            if (q4 <= 244) *(float4*)d1 = o1;
            else           *(float2*)d1 = make_float2(o1.x, o1.y);
        }
        __syncthreads();

        // gather: img rows 3rg..3rg+2 <- convT(stile[bb])
#pragma unroll
        for (int k9 = 0; k9 < 9; ++k9) {
            const int k = 3*rg - 6 + k9;             // s-tile row (wave-uniform)
            if (k >= 0 && k < 16) {
                const float* sp = &stile[bb][k*SRS + q4];
                float4 B0 = *(const float4*)sp;
                float4 B1 = *(const float4*)(sp + 4);
                float4 B2 = *(const float4*)(sp + 8);
                const float win[12] = {B0.x,B0.y,B0.z,B0.w, B1.x,B1.y,B1.z,B1.w,
                                       B2.x,B2.y,B2.z,B2.w};
                if (k9 <= 6)            GATH_ROW(ia0, 6 - k9);
                if (k9 >= 1 && k9 <= 7) GATH_ROW(ia1, 7 - k9);
                if (k9 >= 2)            GATH_ROW(ia2, 8 - k9);
            }
        }
    }

    // image write-out: rows h in [6,15] exclusive -> plain store;
    // boundary rows -> atomicAdd (buffers pre-zeroed by k_res / k_zero)
#pragma unroll
    for (int d = 0; d < 3; ++d) {
        const int h = 3*rg + d;
        if (h < 22) {
            const int habs = p0 + h;
            if (habs < HH) {
                float4 v = (d == 0) ? ia0 : (d == 1) ? ia1 : ia2;
                float* ip = img + (size_t)habs*WW + q4;
                if (h >= 6 && h <= 15) {
                    *(float4*)ip = v;
                } else {
                    atomicAdd(ip + 0, v.x);
                    atomicAdd(ip + 1, v.y);
                    atomicAdd(ip + 2, v.z);
                    atomicAdd(ip + 3, v.w);
                }
            }
        }
    }
}

// ---------------------------------------------------------------------------
// k_res: res = y - ALPHA*((1+cm)X - cm*Xprev) - ((1+cm)U - cm*Uprev);
// save combined X,U for next gen; re-zero the accumulators. All L3-hot.
// ---------------------------------------------------------------------------
__global__ __launch_bounds__(256) void k_res(
    const float* __restrict__ y,
    float* Xp, float* Up,                   // accumulated images (read then zero)
    float* Xc, float* Uc,                   // prev combined (read if cm!=0, then overwrite)
    float* __restrict__ resb, float cm)
{
    int i = blockIdx.x*256 + threadIdx.x;
    if (i >= IMG_TOT/4) return;
    float4 xc = ((const float4*)Xp)[i];
    float4 uc = ((const float4*)Up)[i];
    float4 xo = make_float4(0.f,0.f,0.f,0.f), uo = xo;
    if (cm != 0.f) {
        xo = ((const float4*)Xc)[i];
        uo = ((const float4*)Uc)[i];
    }
    ((float4*)Xc)[i] = xc;
    ((float4*)Uc)[i] = uc;
    float4 z = make_float4(0.f,0.f,0.f,0.f);
    ((float4*)Xp)[i] = z;
    ((float4*)Up)[i] = z;
    float4 yv = ((const float4*)y)[i];
    const float cp = 1.f + cm;
    float4 r;
    r.x = yv.x - ALPHA*(cp*xc.x - cm*xo.x) - (cp*uc.x - cm*uo.x);
    r.y = yv.y - ALPHA*(cp*xc.y - cm*xo.y) - (cp*uc.y - cm*uo.y);
    r.z = yv.z - ALPHA*(cp*xc.z - cm*xo.z) - (cp*uc.z - cm*uo.z);
    r.w = yv.w - ALPHA*(cp*xc.w - cm*xo.w) - (cp*uc.w - cm*uo.w);
    ((float4*)resb)[i] = r;
}

__global__ __launch_bounds__(256) void k_zero2(float* a, float* b)
{
    int i = blockIdx.x*256 + threadIdx.x;
    if (i < IMG_TOT/4) {
        float4 z = make_float4(0.f,0.f,0.f,0.f);
        ((float4*)a)[i] = z;
        ((float4*)b)[i] = z;
    }
}

// k_final: yhat = axh + buh (axh/buh already hold Ax_hat / Bu_hat)
__global__ __launch_bounds__(256) void k_final(
    const float* __restrict__ axh, const float* __restrict__ buh,
    float* __restrict__ yhat)
{
    int i = blockIdx.x*256 + threadIdx.x;
    if (i < IMG_TOT/4) {
        float4 x = ((const float4*)axh)[i];
        float4 u = ((const float4*)buh)[i];
        float4 s;
        s.x = x.x + u.x; s.y = x.y + u.y; s.z = x.z + u.z; s.w = x.w + u.w;
        ((float4*)yhat)[i] = s;
    }
}

extern "C" void kernel_launch(void* const* d_in, const int* in_sizes, int n_in,
                              void* d_out, int out_size, void* d_ws, size_t ws_size,
                              hipStream_t stream) {
    const float* y = (const float*)d_in[0];
    const float* A = (const float*)d_in[1];
    const float* B = (const float*)d_in[2];

    float* out  = (float*)d_out;
    float* yhat = out;                          // [IMG_TOT]
    float* xout = out + IMG_TOT;                // [FLD_TOT]  s_15 x
    float* uout = xout + FLD_TOT;               // [FLD_TOT]  s_15 u
    float* axh  = uout + FLD_TOT;               // [IMG_TOT]  X accumulator / Ax_hat
    float* buh  = axh + IMG_TOT;                // [IMG_TOT]  U accumulator / Bu_hat

    float* ws   = (float*)d_ws;                 // needs 2*FLD_TOT + 2*IMG_TOT (264 MB)
    float* Px0  = ws;                           // [FLD_TOT]
    float* Pu0  = Px0 + FLD_TOT;                // [FLD_TOT]
    float* Xc   = Pu0 + FLD_TOT;                // [IMG_TOT]  combined X (prev gen)
    float* Uc   = Xc + IMG_TOT;                 // [IMG_TOT]  combined U (prev gen)

    // State ping-pong. k_step(t) reads s_t from P[t&1], writes s_{t+1} into
    // P[(t+1)&1] (also holds s_{t-1} = momentum "old"; exact-offset
    // read-then-write per thread). t=14 writes into P[1] = d_out slots.
    float* Px[2] = {Px0, xout};
    float* Pu[2] = {Pu0, uout};
    float* res   = yhat;                        // borrowed; rewritten by k_final

    // FISTA momentum coefficients; step t (>=1) uses cv[t-1]; cv[0]==0.
    float cv[15];
    {
        float t = 1.0f;
        for (int k = 0; k < 15; ++k) {
            float tn = (1.0f + sqrtf(1.0f + 4.0f*t*t)) * 0.5f;
            cv[k] = (t - 1.0f) / tn;
            t = tn;
        }
    }

    dim3 blk512(512), blk256(256);
    dim3 gS(16, 2, NB);                         // (p-tile, field, n)
    int  gE = (IMG_TOT/4 + 255)/256;

    k_zero2<<<gE, blk256, 0, stream>>>(axh, buh);

    // t = 0: res == y, no state reads; writes s_1 + accumulates gen-1 images
    k_step<<<gS, blk512, 0, stream>>>(y, Px[0], Pu[0], Px[1], Pu[1],
                                      axh, buh, A, B, 0.0f, 1);

    for (int t = 1; t < 15; ++t) {
        float cm = cv[t-1];
        k_res<<<gE, blk256, 0, stream>>>(y, axh, buh, Xc, Uc, res, cm);
        k_step<<<gS, blk512, 0, stream>>>(res, Px[t&1], Pu[t&1],
                                          Px[(t+1)&1], Pu[(t+1)&1],
                                          axh, buh, A, B, cm, 0);
    }

    k_final<<<gE, blk256, 0, stream>>>(axh, buh, yhat);
}

// Round 20
// 3815.742 us; speedup vs baseline: 1.5630x; 1.0108x over previous
//
#include <hip/hip_runtime.h>
#include <cmath>

// ---- problem constants ----
#define NB 16
#define CC 32          // channels per dictionary (A and B each)
#define HH 256
#define WW 256
#define DD 250         // 256 - 7 + 1
#define ALPHA 2.0f     // 1 + 1/RHO
#define INVL 0.1f      // 1/L
#define THR 0.01f      // LAM/L

#define IMG_SZ (HH*WW)                       // 65536
#define IMG_TOT (NB*IMG_SZ)                  // 1,048,576
#define FLD_SZ (DD*DD)                       // 62,500
#define FLD_TOT ((size_t)NB*CC*FLD_SZ)       // 32,000,000

#define SRS 264                              // LDS row stride (floats)

// block-uniform float -> SGPR (filter taps become the s-operand of v_fma)
__device__ __forceinline__ float rfl(float x) {
    return __int_as_float(__builtin_amdgcn_readfirstlane(__float_as_int(x)));
}
__device__ __forceinline__ float sthr(float v) {
    float a = fabsf(v) - THR; a = a > 0.f ? a : 0.f;
    return (v > 0.f) ? a : ((v < 0.f) ? -a : 0.f);
}

// conv: out[e][j] += wt[a][b] * res[row][q4 + b + j]   (win = res cols q4..q4+11)
#define CONV_ROW(ACC, Aa) do { \
    _Pragma("unroll") \
    for (int b = 0; b < 7; ++b) { \
        const float wv = wt[Aa][b]; \
        ACC.x += wv*win[b+0]; ACC.y += wv*win[b+1]; \
        ACC.z += wv*win[b+2]; ACC.w += wv*win[b+3]; \
    } } while (0)

// gather (convT): img[d][j] += wt[a][b] * s[k][w4 + j - b]
// win = stile cols (cs) w4..w4+11 where cs = scol + 8 -> idx = 8 + j - b
#define GATH_ROW(ACC, Aa) do { \
    _Pragma("unroll") \
    for (int b = 0; b < 7; ++b) { \
        const float wv = wt[Aa][b]; \
        ACC.x += wv*win[8-b+0]; ACC.y += wv*win[8-b+1]; \
        ACC.z += wv*win[8-b+2]; ACC.w += wv*win[8-b+3]; \
    } } while (0)

// ---------------------------------------------------------------------------
// k_step v17: v16 (proven 3.86 ms) with SINGLE-buffer s-tile:
// LDS 57344 -> ~40960 B, 2 blocks/CU -> 4 blocks/CU. VGPR stays capped at 64
// via __launch_bounds__(512,4) (spill-free per v16's counters); 64 VGPR
// permits 8 waves/SIMD so LDS was the only occupancy cap. Cost: 2 barriers
// per channel (prev-gather-done before stile write; write-visible before
// gather) -- hidden by the doubled wave residency.
// ---------------------------------------------------------------------------
__global__ __launch_bounds__(512, 4) void k_step(
    const float* __restrict__ rin,          // res image (or y at step 0)
    const float* sx_cur, const float* su_cur,
    float* sx_on, float* su_on,             // s_old == s_next (read then write)
    float* __restrict__ Ximg, float* __restrict__ Uimg,  // accumulated convT images
    const float* __restrict__ Afil, const float* __restrict__ Bfil,
    float cmom, int first)
{
    __shared__ __align__(16) float resT[22*SRS];
    __shared__ __align__(16) float stile[16*SRS];

    const int p0  = blockIdx.x * 16;
    const int f   = blockIdx.y;
    const int n   = blockIdx.z;
    const int tid = threadIdx.x;
    const bool isx = (f == 0);

    // zero the s-tile buffer once (borders + beyond-DD rows rely on this)
    {
        float4 z = make_float4(0.f,0.f,0.f,0.f);
        float4* sp = (float4*)&stile[0];
        for (int i = tid; i < 16*SRS/4; i += 512) sp[i] = z;
    }
    // stage res tile rows [p0 .. p0+21], cols 0..255 (+8 zero cols pad)
    {
        const float* rb = rin + (size_t)n * IMG_SZ;
        for (int i = tid; i < 22*66; i += 512) {
            int r  = i / 66;
            int c4 = (i - r*66) << 2;
            int gr = p0 + r;
            float4 v = make_float4(0.f,0.f,0.f,0.f);
            if (gr < HH && c4 < WW) v = *(const float4*)(rb + gr*WW + c4);
            *(float4*)&resT[r*SRS + c4] = v;
        }
    }
    __syncthreads();

    const int rg  = tid >> 6;               // 0..7 (wave-uniform)
    const int q4  = (tid & 63) << 2;        // 0..252
    const bool qok = (q4 <= 248);           // q4==252 lanes idle for conv/state
    const int p_0 = p0 + 2*rg;              // conv output rows p_0, p_0+1

    const float* Wb   = isx ? Afil : Bfil;
    const float* scur = isx ? sx_cur : su_cur;
    float*       sON  = isx ? sx_on  : su_on;    // old AND next
    float*       img  = (isx ? Ximg : Uimg) + (size_t)n * IMG_SZ;

    const bool momentum = (!first) && (cmom != 0.f);
    const bool plain    = (!first) && (cmom == 0.f);

    float4 ia0 = make_float4(0.f,0.f,0.f,0.f), ia1 = ia0, ia2 = ia0;

    const size_t fbase = (size_t)n * CC * FLD_SZ;
    const bool r0ok = qok && (p_0     < DD);
    const bool r1ok = qok && (p_0 + 1 < DD);
    const size_t off0 = fbase + (size_t)p_0*DD + q4;       // + c*FLD_SZ
    const size_t off1 = off0 + DD;

    for (int c = 0; c < CC; ++c) {
        // filter taps -> SGPRs
        float wt[7][7];
        {
            const float* Wp = Wb + c*49;
#pragma unroll
            for (int a = 0; a < 7; ++a)
#pragma unroll
                for (int b = 0; b < 7; ++b)
                    wt[a][b] = rfl(Wp[a*7 + b]);
        }

        // state loads early (float4 reads may overhang 2 floats into the
        // adjacent buffer at q4==248 -- memory-safe by layout; .zw unused)
        const size_t co = (size_t)c * FLD_SZ;
        float4 sc0 = make_float4(0.f,0.f,0.f,0.f), sc1 = sc0, so0 = sc0, so1 = sc0;
        if (momentum) {
            if (r0ok) { sc0 = *(const float4*)(scur + co + off0);
                        so0 = *(const float4*)(sON  + co + off0); }
            if (r1ok) { sc1 = *(const float4*)(scur + co + off1);
                        so1 = *(const float4*)(sON  + co + off1); }
        } else if (plain) {
            if (r0ok) sc0 = *(const float4*)(scur + co + off0);
            if (r1ok) sc1 = *(const float4*)(scur + co + off1);
        }

        // conv: rows p_0, p_0+1 from res rows (2rg .. 2rg+7)
        float4 a0 = make_float4(0.f,0.f,0.f,0.f), a1 = a0;
#pragma unroll
        for (int rr = 0; rr < 8; ++rr) {
            const float* lp = &resT[(2*rg + rr)*SRS + q4];
            float4 A0 = *(const float4*)lp;
            float4 A1 = *(const float4*)(lp + 4);
            float4 A2 = *(const float4*)(lp + 8);
            const float win[12] = {A0.x,A0.y,A0.z,A0.w, A1.x,A1.y,A1.z,A1.w,
                                   A2.x,A2.y,A2.z,A2.w};
            if (rr <= 6) CONV_ROW(a0, rr);       // e=0: a = rr
            if (rr >= 1) CONV_ROW(a1, rr-1);     // e=1: a = rr-1
        }

        // epilogue: s_next values
        float4 o0 = make_float4(a0.x*INVL, a0.y*INVL, a0.z*INVL, a0.w*INVL);
        float4 o1 = make_float4(a1.x*INVL, a1.y*INVL, a1.z*INVL, a1.w*INVL);
        if (momentum) {
            o0.x += sc0.x + cmom*(sc0.x - so0.x);
            o0.y += sc0.y + cmom*(sc0.y - so0.y);
            o0.z += sc0.z + cmom*(sc0.z - so0.z);
            o0.w += sc0.w + cmom*(sc0.w - so0.w);
            o1.x += sc1.x + cmom*(sc1.x - so1.x);
            o1.y += sc1.y + cmom*(sc1.y - so1.y);
            o1.z += sc1.z + cmom*(sc1.z - so1.z);
            o1.w += sc1.w + cmom*(sc1.w - so1.w);
        } else if (plain) {
            o0.x += sc0.x; o0.y += sc0.y; o0.z += sc0.z; o0.w += sc0.w;
            o1.x += sc1.x; o1.y += sc1.y; o1.z += sc1.z; o1.w += sc1.w;
        }
        if (!isx) {
            o0.x = sthr(o0.x); o0.y = sthr(o0.y); o0.z = sthr(o0.z); o0.w = sthr(o0.w);
            o1.x = sthr(o1.x); o1.y = sthr(o1.y); o1.z = sthr(o1.z); o1.w = sthr(o1.w);
        }

        // global store of s_next (no LDS hazard; before the barriers)
        if (r0ok) {
            float* dst = sON + co + off0;
            if (q4 <= 244) *(float4*)dst = o0;
            else           *(float2*)dst = make_float2(o0.x, o0.y);
        }
        if (r1ok) {
            float* dst = sON + co + off1;
            if (q4 <= 244) *(float4*)dst = o1;
            else           *(float2*)dst = make_float2(o1.x, o1.y);
        }

        __syncthreads();                     // gather(c-1) on stile complete

        if (r0ok) {
            float* d0 = &stile[(2*rg)*SRS + q4 + 8];
            if (q4 <= 244) *(float4*)d0 = o0;
            else           *(float2*)d0 = make_float2(o0.x, o0.y);
        }
        if (r1ok) {
            float* d1 = &stile[(2*rg + 1)*SRS + q4 + 8];
            if (q4 <= 244) *(float4*)d1 = o1;
            else           *(float2*)d1 = make_float2(o1.x, o1.y);
        }
        __syncthreads();                     // stile writes visible

        // gather: img rows 3rg..3rg+2 <- convT(stile)
#pragma unroll
        for (int k9 = 0; k9 < 9; ++k9) {
            const int k = 3*rg - 6 + k9;             // s-tile row (wave-uniform)
            if (k >= 0 && k < 16) {
                const float* sp = &stile[k*SRS + q4];
                float4 B0 = *(const float4*)sp;
                float4 B1 = *(const float4*)(sp + 4);
                float4 B2 = *(const float4*)(sp + 8);
                const float win[12] = {B0.x,B0.y,B0.z,B0.w, B1.x,B1.y,B1.z,B1.w,
                                       B2.x,B2.y,B2.z,B2.w};
                if (k9 <= 6)            GATH_ROW(ia0, 6 - k9);
                if (k9 >= 1 && k9 <= 7) GATH_ROW(ia1, 7 - k9);
                if (k9 >= 2)            GATH_ROW(ia2, 8 - k9);
            }
        }
    }

    // image write-out: rows h in [6,15] exclusive -> plain store;
    // boundary rows -> atomicAdd (buffers pre-zeroed by k_res / k_zero)
#pragma unroll
    for (int d = 0; d < 3; ++d) {
        const int h = 3*rg + d;
        if (h < 22) {
            const int habs = p0 + h;
            if (habs < HH) {
                float4 v = (d == 0) ? ia0 : (d == 1) ? ia1 : ia2;
                float* ip = img + (size_t)habs*WW + q4;
                if (h >= 6 && h <= 15) {
                    *(float4*)ip = v;
                } else {
                    atomicAdd(ip + 0, v.x);
                    atomicAdd(ip + 1, v.y);
                    atomicAdd(ip + 2, v.z);
                    atomicAdd(ip + 3, v.w);
                }
            }
        }
    }
}

// ---------------------------------------------------------------------------
// k_res: res = y - ALPHA*((1+cm)X - cm*Xprev) - ((1+cm)U - cm*Uprev);
// save combined X,U for next gen; re-zero the accumulators. All L3-hot.
// ---------------------------------------------------------------------------
__global__ __launch_bounds__(256) void k_res(
    const float* __restrict__ y,
    float* Xp, float* Up,                   // accumulated images (read then zero)
    float* Xc, float* Uc,                   // prev combined (read if cm!=0, then overwrite)
    float* __restrict__ resb, float cm)
{
    int i = blockIdx.x*256 + threadIdx.x;
    if (i >= IMG_TOT/4) return;
    float4 xc = ((const float4*)Xp)[i];
    float4 uc = ((const float4*)Up)[i];
    float4 xo = make_float4(0.f,0.f,0.f,0.f), uo = xo;
    if (cm != 0.f) {
        xo = ((const float4*)Xc)[i];
        uo = ((const float4*)Uc)[i];
    }
    ((float4*)Xc)[i] = xc;
    ((float4*)Uc)[i] = uc;
    float4 z = make_float4(0.f,0.f,0.f,0.f);
    ((float4*)Xp)[i] = z;
    ((float4*)Up)[i] = z;
    float4 yv = ((const float4*)y)[i];
    const float cp = 1.f + cm;
    float4 r;
    r.x = yv.x - ALPHA*(cp*xc.x - cm*xo.x) - (cp*uc.x - cm*uo.x);
    r.y = yv.y - ALPHA*(cp*xc.y - cm*xo.y) - (cp*uc.y - cm*uo.y);
    r.z = yv.z - ALPHA*(cp*xc.z - cm*xo.z) - (cp*uc.z - cm*uo.z);
    r.w = yv.w - ALPHA*(cp*xc.w - cm*xo.w) - (cp*uc.w - cm*uo.w);
    ((float4*)resb)[i] = r;
}

__global__ __launch_bounds__(256) void k_zero2(float* a, float* b)
{
    int i = blockIdx.x*256 + threadIdx.x;
    if (i < IMG_TOT/4) {
        float4 z = make_float4(0.f,0.f,0.f,0.f);
        ((float4*)a)[i] = z;
        ((float4*)b)[i] = z;
    }
}

// k_final: yhat = axh + buh (axh/buh already hold Ax_hat / Bu_hat)
__global__ __launch_bounds__(256) void k_final(
    const float* __restrict__ axh, const float* __restrict__ buh,
    float* __restrict__ yhat)
{
    int i = blockIdx.x*256 + threadIdx.x;
    if (i < IMG_TOT/4) {
        float4 x = ((const float4*)axh)[i];
        float4 u = ((const float4*)buh)[i];
        float4 s;
        s.x = x.x + u.x; s.y = x.y + u.y; s.z = x.z + u.z; s.w = x.w + u.w;
        ((float4*)yhat)[i] = s;
    }
}

extern "C" void kernel_launch(void* const* d_in, const int* in_sizes, int n_in,
                              void* d_out, int out_size, void* d_ws, size_t ws_size,
                              hipStream_t stream) {
    const float* y = (const float*)d_in[0];
    const float* A = (const float*)d_in[1];
    const float* B = (const float*)d_in[2];

    float* out  = (float*)d_out;
    float* yhat = out;                          // [IMG_TOT]
    float* xout = out + IMG_TOT;                // [FLD_TOT]  s_15 x
    float* uout = xout + FLD_TOT;               // [FLD_TOT]  s_15 u
    float* axh  = uout + FLD_TOT;               // [IMG_TOT]  X accumulator / Ax_hat
    float* buh  = axh + IMG_TOT;                // [IMG_TOT]  U accumulator / Bu_hat

    float* ws   = (float*)d_ws;                 // needs 2*FLD_TOT + 2*IMG_TOT (264 MB)
    float* Px0  = ws;                           // [FLD_TOT]
    float* Pu0  = Px0 + FLD_TOT;                // [FLD_TOT]
    float* Xc   = Pu0 + FLD_TOT;                // [IMG_TOT]  combined X (prev gen)
    float* Uc   = Xc + IMG_TOT;                 // [IMG_TOT]  combined U (prev gen)

    // State ping-pong. k_step(t) reads s_t from P[t&1], writes s_{t+1} into
    // P[(t+1)&1] (also holds s_{t-1} = momentum "old"; exact-offset
    // read-then-write per thread). t=14 writes into P[1] = d_out slots.
    float* Px[2] = {Px0, xout};
    float* Pu[2] = {Pu0, uout};
    float* res   = yhat;                        // borrowed; rewritten by k_final

    // FISTA momentum coefficients; step t (>=1) uses cv[t-1]; cv[0]==0.
    float cv[15];
    {
        float t = 1.0f;
        for (int k = 0; k < 15; ++k) {
            float tn = (1.0f + sqrtf(1.0f + 4.0f*t*t)) * 0.5f;
            cv[k] = (t - 1.0f) / tn;
            t = tn;
        }
    }

    dim3 blk512(512), blk256(256);
    dim3 gS(16, 2, NB);                         // (p-tile, field, n)
    int  gE = (IMG_TOT/4 + 255)/256;

    k_zero2<<<gE, blk256, 0, stream>>>(axh, buh);

    // t = 0: res == y, no state reads; writes s_1 + accumulates gen-1 images
    k_step<<<gS, blk512, 0, stream>>>(y, Px[0], Pu[0], Px[1], Pu[1],
                                      axh, buh, A, B, 0.0f, 1);

    for (int t = 1; t < 15; ++t) {
        float cm = cv[t-1];
        k_res<<<gE, blk256, 0, stream>>>(y, axh, buh, Xc, Uc, res, cm);
        k_step<<<gS, blk512, 0, stream>>>(res, Px[t&1], Pu[t&1],
                                          Px[(t+1)&1], Pu[(t+1)&1],
                                          axh, buh, A, B, cm, 0);
    }

    k_final<<<gE, blk256, 0, stream>>>(axh, buh, yhat);
}